// Round 12
// baseline (123.418 us; speedup 1.0000x reference)
//
#include <hip/hip_runtime.h>
#include <math.h>

// NaiveDFTQNN: 25-wire state vector, DIM = 2^25.
// out = (cos(theta[0]/2)/||f||) * (tensor product of 12 Givens rotations) * f
// Pair j (j=0..11) acts on little-endian element bits (2j+1, 2j), angle theta[11-j]/2:
//   v=01: n01 = c*a01 - s*a10 ; v=10: n10 = s*a01 + c*a10 ; v=00,11 untouched.
// Bit 24 (wire 0) is a spectator (RX folds into the scalar).
//
// r9-champion steering (r11 A/B confirmed): `in` NT-loaded (HBM stream, no IC
// allocate); intermediate regular-stored by p1 (IC-resident) and NT-loaded by
// high; final result NT-stored. IC holds only the 128 MB intermediate.
// Schedules: p1 = 256 thr x 16 quads x 2 tiles, all 32 loads issued upfront
// (MLP-limited), 64 KB LDS, lgkm-only barriers; high = 512 thr x 16 quads
// x 2 tiles (b24=0/1), 128 KB LDS, 1 LDS trip, 128 B granules.
// r12 tweak: p1 sumsq via fp32 pairwise tree (kills 128 cvt + 128 dfma per
// thread off the critical path); f64 only for the cross-lane reduce.

typedef float f32x4 __attribute__((ext_vector_type(4)));

static __device__ __forceinline__ float4 nt_load4(const float* p) {
    f32x4 v = __builtin_nontemporal_load((const f32x4*)p);
    return *(float4*)&v;
}
static __device__ __forceinline__ void nt_store4(float* p, float4 v) {
    __builtin_nontemporal_store(*(f32x4*)&v, (f32x4*)p);
}

// Barrier that drains ONLY lgkmcnt (LDS) — global loads/stores stay in flight.
static __device__ __forceinline__ void bar_lgkm() {
    asm volatile("s_waitcnt lgkmcnt(0)\n\ts_barrier" ::: "memory");
}

static __device__ __forceinline__ void rot4(float4& a, float4& b, float c, float s) {
    float4 na, nb;
    na.x = c*a.x - s*b.x;  nb.x = s*a.x + c*b.x;
    na.y = c*a.y - s*b.y;  nb.y = s*a.y + c*b.y;
    na.z = c*a.z - s*b.z;  nb.z = s*a.z + c*b.z;
    na.w = c*a.w - s*b.w;  nb.w = s*a.w + c*b.w;
    a = na; b = nb;
}

static __device__ __forceinline__ float4 shflx4(float4 v, int m) {
    float4 r;
    r.x = __shfl_xor(v.x, m, 64);
    r.y = __shfl_xor(v.y, m, 64);
    r.z = __shfl_xor(v.z, m, 64);
    r.w = __shfl_xor(v.w, m, 64);
    return r;
}

template <int NR>
static __device__ __forceinline__ void rotshfl(float4* f, int sh, float c, float s, int lane) {
    const int pv = (lane >> sh) & 3;
    const bool act = (pv == 1) || (pv == 2);
    const float cl = act ? c : 1.0f;
    const float sl = act ? ((pv == 1) ? -s : s) : 0.0f;
    const int m = 3 << sh;
#pragma unroll
    for (int k = 0; k < NR; ++k) {
        float4 p = shflx4(f[k], m);
        float4 n;
        n.x = fmaf(sl, p.x, cl * f[k].x);
        n.y = fmaf(sl, p.y, cl * f[k].y);
        n.z = fmaf(sl, p.z, cl * f[k].z);
        n.w = fmaf(sl, p.w, cl * f[k].w);
        f[k] = n;
    }
}

// fp32 pairwise-tree sum of squares over 16 float4 (64 values).
static __device__ __forceinline__ float sumsq16(const float4* f) {
    float q[16];
#pragma unroll
    for (int k = 0; k < 16; ++k)
        q[k] = fmaf(f[k].x, f[k].x,
               fmaf(f[k].y, f[k].y,
               fmaf(f[k].z, f[k].z, f[k].w * f[k].w)));
#pragma unroll
    for (int st = 1; st < 16; st <<= 1)
#pragma unroll
        for (int i = 0; i < 16; i += (st << 1))
            q[i] += q[i + st];
    return q[0];
}

// ---------------- qnn_p1: pairs j0..j6 (el bits 0..13), in -> out, + partials ------
// Tile = contiguous 4096 quads (s bits 0..11 = el bits 2..13); 2 tiles/block.
// Load layout  s = w2<<10 | k<<6 | lane: j0 components; j1/j2/j3 lane shfl
// (s bits 1,0/3,2/5,4); j4 = k bits 1,0; j5 = k bits 3,2.
// LDS exchange to s' = m<<8 | w2<<6 | lane: j6 = m bits 3,2. Store at s'.
// Pipeline: loadA,loadB | rotA,writeA | BAR | readA,j6A,storeA,rotB | BAR |
//           writeB | BAR | readB,j6B,storeB.  (BAR = lgkm-only)
__global__ __launch_bounds__(256, 2) void qnn_p1(const float* __restrict__ in,
                                                 const float* __restrict__ theta,
                                                 float* __restrict__ out,
                                                 double* __restrict__ partials) {
    __shared__ __align__(16) float4 lds[4096];   // 64 KB
    __shared__ double red[4];
    const int t = threadIdx.x, lane = t & 63, w2 = t >> 6;
    const long gA = (long)blockIdx.x << 13;      // quad base, tile A
    const long gB = gA + 4096;                   // tile B

    float c0,s0,c1,s1,c2,s2,c3,s3,c4,s4,c5,s5,c6,s6;
    { float th;
      th=0.5f*theta[11]; c0=cosf(th); s0=sinf(th);
      th=0.5f*theta[10]; c1=cosf(th); s1=sinf(th);
      th=0.5f*theta[9];  c2=cosf(th); s2=sinf(th);
      th=0.5f*theta[8];  c3=cosf(th); s3=sinf(th);
      th=0.5f*theta[7];  c4=cosf(th); s4=sinf(th);
      th=0.5f*theta[6];  c5=cosf(th); s5=sinf(th);
      th=0.5f*theta[5];  c6=cosf(th); s6=sinf(th); }

    float4 f[16], g[16];
    // ---- issue ALL 32 loads (B's stay in flight deep into A's processing) ----
#pragma unroll
    for (int k = 0; k < 16; ++k)
        f[k] = nt_load4(in + ((gA + ((w2 << 10) | (k << 6) | lane)) << 2));
#pragma unroll
    for (int k = 0; k < 16; ++k)
        g[k] = nt_load4(in + ((gB + ((w2 << 10) | (k << 6) | lane)) << 2));

    const float sA = sumsq16(f);

    // ---- tile A: register rotations j0..j5 ----
#pragma unroll
    for (int k = 0; k < 16; ++k) {
        float ny = c0*f[k].y - s0*f[k].z;
        float nz = s0*f[k].y + c0*f[k].z;
        f[k].y = ny; f[k].z = nz;
    }
    rotshfl<16>(f, 0, c1, s1, lane);
    rotshfl<16>(f, 2, c2, s2, lane);
    rotshfl<16>(f, 4, c3, s3, lane);
#pragma unroll
    for (int hi = 0; hi < 16; hi += 4) rot4(f[hi+1], f[hi+2], c4, s4);
#pragma unroll
    for (int lo = 0; lo < 4; ++lo)     rot4(f[4+lo], f[8+lo], c5, s5);

#pragma unroll
    for (int k = 0; k < 16; ++k) lds[(w2 << 10) | (k << 6) | lane] = f[k];
    bar_lgkm();
    // ---- read A at s' = m<<8 | w2<<6 | lane; j6 = m bits 3,2; store ----
#pragma unroll
    for (int m = 0; m < 16; ++m) f[m] = lds[(m << 8) | (w2 << 6) | lane];
#pragma unroll
    for (int lo = 0; lo < 4; ++lo) rot4(f[4+lo], f[8+lo], c6, s6);
#pragma unroll
    for (int m = 0; m < 16; ++m)
        *(float4*)(out + ((gA + ((m << 8) | (w2 << 6) | lane)) << 2)) = f[m];

    // ---- tile B register rotations (loads long since landed) ----
    const float sB = sumsq16(g);
#pragma unroll
    for (int k = 0; k < 16; ++k) {
        float ny = c0*g[k].y - s0*g[k].z;
        float nz = s0*g[k].y + c0*g[k].z;
        g[k].y = ny; g[k].z = nz;
    }
    rotshfl<16>(g, 0, c1, s1, lane);
    rotshfl<16>(g, 2, c2, s2, lane);
    rotshfl<16>(g, 4, c3, s3, lane);
#pragma unroll
    for (int hi = 0; hi < 16; hi += 4) rot4(g[hi+1], g[hi+2], c4, s4);
#pragma unroll
    for (int lo = 0; lo < 4; ++lo)     rot4(g[4+lo], g[8+lo], c5, s5);

    bar_lgkm();   // all waves done reading A's LDS image
#pragma unroll
    for (int k = 0; k < 16; ++k) lds[(w2 << 10) | (k << 6) | lane] = g[k];
    bar_lgkm();
#pragma unroll
    for (int m = 0; m < 16; ++m) g[m] = lds[(m << 8) | (w2 << 6) | lane];
#pragma unroll
    for (int lo = 0; lo < 4; ++lo) rot4(g[4+lo], g[8+lo], c6, s6);
#pragma unroll
    for (int m = 0; m < 16; ++m)
        *(float4*)(out + ((gB + ((m << 8) | (w2 << 6) | lane)) << 2)) = g[m];

    // ---- deterministic sumsq partial (f64 from here) ----
    double acc = (double)sA + (double)sB;
#pragma unroll
    for (int off = 32; off > 0; off >>= 1) acc += __shfl_down(acc, off, 64);
    if (lane == 0) red[w2] = acc;
    bar_lgkm();
    if (t == 0)
        partials[blockIdx.x] = red[0] + red[1] + red[2] + red[3];
}

// ---------------- Norm: 1024 partials -> scale = cos(theta[0]/2)/sqrt(sum) ---------
__global__ void qnn_norm(const double* __restrict__ partials,
                         const float* __restrict__ theta,
                         double* __restrict__ scale) {
    __shared__ double w[4];
    const int t = threadIdx.x;
    double acc = 0.0;
    for (int i = t; i < 1024; i += 256) acc += partials[i];
#pragma unroll
    for (int off = 32; off > 0; off >>= 1) acc += __shfl_down(acc, off, 64);
    if ((t & 63) == 0) w[t >> 6] = acc;
    __syncthreads();
    if (t == 0) {
        double tot = w[0] + w[1] + w[2] + w[3];
        *scale = (double)cosf(0.5f * theta[0]) / sqrt(tot);
    }
}

// ---------------- qnn_high: pairs j7..j11 (el bits 14..23) + scale, in place -------
// Tile: slot s (13 bits) = H<<3 | pq; H = el bits 14..23, pq = el bits 2..4.
// Global quad = b24<<22 | H<<12 | mid<<3 | pq (mid = el bits 5..13, grid 512;
// both b24 tiles per block). 128 B granules at 64 KB stride.
// Load layout s = k<<9 | t (512 thr, k=0..15): j7 = s bits 4,3 (lane shfl);
// j10 = s bits 10,9 = k bits 1,0; j11 = s bits 12,11 = k bits 3,2.
// LDS exchange to s' = w3<<10 | (lane>>5)<<9 | m<<5 | (lane&31):
// j8 = s bits 6,5 = m bits 1,0; j9 = s bits 8,7 = m bits 3,2. NT store at s'.
// NT loads (read-once; IC hit still served, no re-allocation churn).
__global__ __launch_bounds__(512, 2) void qnn_high(float* __restrict__ buf,
                                                   const float* __restrict__ theta,
                                                   const double* __restrict__ scale) {
    __shared__ __align__(16) float4 lds[8192];   // 128 KB
    const int t = threadIdx.x, lane = t & 63, w3 = t >> 6;
    const int mid = blockIdx.x;
    const long gqA = (long)mid << 3;                 // b24 = 0
    const long gqB = (1L << 22) | ((long)mid << 3);  // b24 = 1

    float c7,s7,c8,s8,c9,s9,c10,s10,c11,s11;
    { float th;
      th=0.5f*theta[4]; c7 =cosf(th); s7 =sinf(th);
      th=0.5f*theta[3]; c8 =cosf(th); s8 =sinf(th);
      th=0.5f*theta[2]; c9 =cosf(th); s9 =sinf(th);
      th=0.5f*theta[1]; c10=cosf(th); s10=sinf(th);
      th=0.5f*theta[0]; c11=cosf(th); s11=sinf(th); }
    const float sc = (float)(*scale);

    const int rbase = (w3 << 10) | ((lane >> 5) << 9) | (lane & 31);  // read base

    float4 f[16], g[16];
    // ---- issue ALL 32 loads ----
#pragma unroll
    for (int k = 0; k < 16; ++k) {
        const int s_ = (k << 9) | t;
        f[k] = nt_load4(buf + ((gqA | ((long)(s_ >> 3) << 12) | (s_ & 7)) << 2));
    }
#pragma unroll
    for (int k = 0; k < 16; ++k) {
        const int s_ = (k << 9) | t;
        g[k] = nt_load4(buf + ((gqB | ((long)(s_ >> 3) << 12) | (s_ & 7)) << 2));
    }

    // ---- tile A: j7 (shfl), j10/j11 (regs) ----
    rotshfl<16>(f, 3, c7, s7, lane);
#pragma unroll
    for (int hi = 0; hi < 16; hi += 4) rot4(f[hi+1], f[hi+2], c10, s10);
#pragma unroll
    for (int lo = 0; lo < 4; ++lo)     rot4(f[4+lo], f[8+lo], c11, s11);
#pragma unroll
    for (int k = 0; k < 16; ++k) lds[(k << 9) | t] = f[k];
    bar_lgkm();
    // ---- read A; j8/j9 (regs); scale; NT store ----
#pragma unroll
    for (int m = 0; m < 16; ++m) f[m] = lds[rbase | (m << 5)];
#pragma unroll
    for (int hi = 0; hi < 16; hi += 4) rot4(f[hi+1], f[hi+2], c8, s8);
#pragma unroll
    for (int lo = 0; lo < 4; ++lo)     rot4(f[4+lo], f[8+lo], c9, s9);
#pragma unroll
    for (int m = 0; m < 16; ++m) {
        const int s_ = rbase | (m << 5);
        float4 v = f[m];
        v.x *= sc; v.y *= sc; v.z *= sc; v.w *= sc;
        nt_store4(buf + ((gqA | ((long)(s_ >> 3) << 12) | (s_ & 7)) << 2), v);
    }

    // ---- tile B ----
    rotshfl<16>(g, 3, c7, s7, lane);
#pragma unroll
    for (int hi = 0; hi < 16; hi += 4) rot4(g[hi+1], g[hi+2], c10, s10);
#pragma unroll
    for (int lo = 0; lo < 4; ++lo)     rot4(g[4+lo], g[8+lo], c11, s11);
    bar_lgkm();   // all waves done reading A's LDS image
#pragma unroll
    for (int k = 0; k < 16; ++k) lds[(k << 9) | t] = g[k];
    bar_lgkm();
#pragma unroll
    for (int m = 0; m < 16; ++m) g[m] = lds[rbase | (m << 5)];
#pragma unroll
    for (int hi = 0; hi < 16; hi += 4) rot4(g[hi+1], g[hi+2], c8, s8);
#pragma unroll
    for (int lo = 0; lo < 4; ++lo)     rot4(g[4+lo], g[8+lo], c9, s9);
#pragma unroll
    for (int m = 0; m < 16; ++m) {
        const int s_ = rbase | (m << 5);
        float4 v = g[m];
        v.x *= sc; v.y *= sc; v.z *= sc; v.w *= sc;
        nt_store4(buf + ((gqB | ((long)(s_ >> 3) << 12) | (s_ & 7)) << 2), v);
    }
}

extern "C" void kernel_launch(void* const* d_in, const int* in_sizes, int n_in,
                              void* d_out, int out_size, void* d_ws, size_t ws_size,
                              hipStream_t stream) {
    const float* in = (const float*)d_in[0];      // feature, 2^25 f32
    const float* theta = (const float*)d_in[1];   // 13 f32
    float* out = (float*)d_out;                   // 2^25 f32
    double* part = (double*)d_ws;                 // 1024 partials + 1 scale
    double* scale = part + 1024;

    qnn_p1<<<1024, 256, 0, stream>>>(in, theta, out, part);
    qnn_norm<<<1, 256, 0, stream>>>(part, theta, scale);
    qnn_high<<<512, 512, 0, stream>>>(out, theta, scale);
}

// Round 13
// 97.537 us; speedup vs baseline: 1.2654x; 1.2654x over previous
//
#include <hip/hip_runtime.h>
#include <math.h>

// NaiveDFTQNN: 25-wire state vector, DIM = 2^25.
// out = (cos(theta[0]/2)/||f||) * (tensor product of 12 Givens rotations) * f
// Pair j (j=0..11) acts on little-endian element bits (2j+1, 2j), angle theta[11-j]/2:
//   v=01: n01 = c*a01 - s*a10 ; v=10: n10 = s*a01 + c*a10 ; v=00,11 untouched.
// Bit 24 (wire 0) is a spectator (RX folds into the scalar).
//
// Cache-steering ledger (A/B-mapped over r6..r12):
//   - `in`: NT-load (HBM-cold stream; regular made no difference to p1, NT frees IC)
//   - intermediate: REGULAR store (p1) + REGULAR load (high). r11: NT-store -> +20us.
//     r12: NT-load -> high 35->80us. NT anywhere on this buffer loses.
//   - final output: NT-store (nobody re-reads).
// p1 = 256 thr x 16 quads x 2 tiles, all 32 loads upfront (MLP-limited),
//      64 KB LDS, lgkm-only barriers, fp32 pairwise sumsq (r12: 55->41us).
// high = 512 thr x 16 quads x 2 tiles (b24=0/1), 128 KB LDS, 1 LDS trip,
//      128 B granules at 64 KB stride.

typedef float f32x4 __attribute__((ext_vector_type(4)));

static __device__ __forceinline__ float4 nt_load4(const float* p) {
    f32x4 v = __builtin_nontemporal_load((const f32x4*)p);
    return *(float4*)&v;
}
static __device__ __forceinline__ void nt_store4(float* p, float4 v) {
    __builtin_nontemporal_store(*(f32x4*)&v, (f32x4*)p);
}

// Barrier that drains ONLY lgkmcnt (LDS) — global loads/stores stay in flight.
static __device__ __forceinline__ void bar_lgkm() {
    asm volatile("s_waitcnt lgkmcnt(0)\n\ts_barrier" ::: "memory");
}

static __device__ __forceinline__ void rot4(float4& a, float4& b, float c, float s) {
    float4 na, nb;
    na.x = c*a.x - s*b.x;  nb.x = s*a.x + c*b.x;
    na.y = c*a.y - s*b.y;  nb.y = s*a.y + c*b.y;
    na.z = c*a.z - s*b.z;  nb.z = s*a.z + c*b.z;
    na.w = c*a.w - s*b.w;  nb.w = s*a.w + c*b.w;
    a = na; b = nb;
}

static __device__ __forceinline__ float4 shflx4(float4 v, int m) {
    float4 r;
    r.x = __shfl_xor(v.x, m, 64);
    r.y = __shfl_xor(v.y, m, 64);
    r.z = __shfl_xor(v.z, m, 64);
    r.w = __shfl_xor(v.w, m, 64);
    return r;
}

template <int NR>
static __device__ __forceinline__ void rotshfl(float4* f, int sh, float c, float s, int lane) {
    const int pv = (lane >> sh) & 3;
    const bool act = (pv == 1) || (pv == 2);
    const float cl = act ? c : 1.0f;
    const float sl = act ? ((pv == 1) ? -s : s) : 0.0f;
    const int m = 3 << sh;
#pragma unroll
    for (int k = 0; k < NR; ++k) {
        float4 p = shflx4(f[k], m);
        float4 n;
        n.x = fmaf(sl, p.x, cl * f[k].x);
        n.y = fmaf(sl, p.y, cl * f[k].y);
        n.z = fmaf(sl, p.z, cl * f[k].z);
        n.w = fmaf(sl, p.w, cl * f[k].w);
        f[k] = n;
    }
}

// fp32 pairwise-tree sum of squares over 16 float4 (64 values).
static __device__ __forceinline__ float sumsq16(const float4* f) {
    float q[16];
#pragma unroll
    for (int k = 0; k < 16; ++k)
        q[k] = fmaf(f[k].x, f[k].x,
               fmaf(f[k].y, f[k].y,
               fmaf(f[k].z, f[k].z, f[k].w * f[k].w)));
#pragma unroll
    for (int st = 1; st < 16; st <<= 1)
#pragma unroll
        for (int i = 0; i < 16; i += (st << 1))
            q[i] += q[i + st];
    return q[0];
}

// ---------------- qnn_p1: pairs j0..j6 (el bits 0..13), in -> out, + partials ------
// Tile = contiguous 4096 quads (s bits 0..11 = el bits 2..13); 2 tiles/block.
// Load layout  s = w2<<10 | k<<6 | lane: j0 components; j1/j2/j3 lane shfl
// (s bits 1,0/3,2/5,4); j4 = k bits 1,0; j5 = k bits 3,2.
// LDS exchange to s' = m<<8 | w2<<6 | lane: j6 = m bits 3,2. Store at s'.
// Pipeline: loadA,loadB | rotA,writeA | BAR | readA,j6A,storeA,rotB | BAR |
//           writeB | BAR | readB,j6B,storeB.  (BAR = lgkm-only)
__global__ __launch_bounds__(256, 2) void qnn_p1(const float* __restrict__ in,
                                                 const float* __restrict__ theta,
                                                 float* __restrict__ out,
                                                 double* __restrict__ partials) {
    __shared__ __align__(16) float4 lds[4096];   // 64 KB
    __shared__ double red[4];
    const int t = threadIdx.x, lane = t & 63, w2 = t >> 6;
    const long gA = (long)blockIdx.x << 13;      // quad base, tile A
    const long gB = gA + 4096;                   // tile B

    float c0,s0,c1,s1,c2,s2,c3,s3,c4,s4,c5,s5,c6,s6;
    { float th;
      th=0.5f*theta[11]; c0=cosf(th); s0=sinf(th);
      th=0.5f*theta[10]; c1=cosf(th); s1=sinf(th);
      th=0.5f*theta[9];  c2=cosf(th); s2=sinf(th);
      th=0.5f*theta[8];  c3=cosf(th); s3=sinf(th);
      th=0.5f*theta[7];  c4=cosf(th); s4=sinf(th);
      th=0.5f*theta[6];  c5=cosf(th); s5=sinf(th);
      th=0.5f*theta[5];  c6=cosf(th); s6=sinf(th); }

    float4 f[16], g[16];
    // ---- issue ALL 32 loads (B's stay in flight deep into A's processing) ----
#pragma unroll
    for (int k = 0; k < 16; ++k)
        f[k] = nt_load4(in + ((gA + ((w2 << 10) | (k << 6) | lane)) << 2));
#pragma unroll
    for (int k = 0; k < 16; ++k)
        g[k] = nt_load4(in + ((gB + ((w2 << 10) | (k << 6) | lane)) << 2));

    const float sA = sumsq16(f);

    // ---- tile A: register rotations j0..j5 ----
#pragma unroll
    for (int k = 0; k < 16; ++k) {
        float ny = c0*f[k].y - s0*f[k].z;
        float nz = s0*f[k].y + c0*f[k].z;
        f[k].y = ny; f[k].z = nz;
    }
    rotshfl<16>(f, 0, c1, s1, lane);
    rotshfl<16>(f, 2, c2, s2, lane);
    rotshfl<16>(f, 4, c3, s3, lane);
#pragma unroll
    for (int hi = 0; hi < 16; hi += 4) rot4(f[hi+1], f[hi+2], c4, s4);
#pragma unroll
    for (int lo = 0; lo < 4; ++lo)     rot4(f[4+lo], f[8+lo], c5, s5);

#pragma unroll
    for (int k = 0; k < 16; ++k) lds[(w2 << 10) | (k << 6) | lane] = f[k];
    bar_lgkm();
    // ---- read A at s' = m<<8 | w2<<6 | lane; j6 = m bits 3,2; store ----
#pragma unroll
    for (int m = 0; m < 16; ++m) f[m] = lds[(m << 8) | (w2 << 6) | lane];
#pragma unroll
    for (int lo = 0; lo < 4; ++lo) rot4(f[4+lo], f[8+lo], c6, s6);
#pragma unroll
    for (int m = 0; m < 16; ++m)
        *(float4*)(out + ((gA + ((m << 8) | (w2 << 6) | lane)) << 2)) = f[m];

    // ---- tile B register rotations (loads long since landed) ----
    const float sB = sumsq16(g);
#pragma unroll
    for (int k = 0; k < 16; ++k) {
        float ny = c0*g[k].y - s0*g[k].z;
        float nz = s0*g[k].y + c0*g[k].z;
        g[k].y = ny; g[k].z = nz;
    }
    rotshfl<16>(g, 0, c1, s1, lane);
    rotshfl<16>(g, 2, c2, s2, lane);
    rotshfl<16>(g, 4, c3, s3, lane);
#pragma unroll
    for (int hi = 0; hi < 16; hi += 4) rot4(g[hi+1], g[hi+2], c4, s4);
#pragma unroll
    for (int lo = 0; lo < 4; ++lo)     rot4(g[4+lo], g[8+lo], c5, s5);

    bar_lgkm();   // all waves done reading A's LDS image
#pragma unroll
    for (int k = 0; k < 16; ++k) lds[(w2 << 10) | (k << 6) | lane] = g[k];
    bar_lgkm();
#pragma unroll
    for (int m = 0; m < 16; ++m) g[m] = lds[(m << 8) | (w2 << 6) | lane];
#pragma unroll
    for (int lo = 0; lo < 4; ++lo) rot4(g[4+lo], g[8+lo], c6, s6);
#pragma unroll
    for (int m = 0; m < 16; ++m)
        *(float4*)(out + ((gB + ((m << 8) | (w2 << 6) | lane)) << 2)) = g[m];

    // ---- deterministic sumsq partial (f64 cross-lane only) ----
    double acc = (double)sA + (double)sB;
#pragma unroll
    for (int off = 32; off > 0; off >>= 1) acc += __shfl_down(acc, off, 64);
    if (lane == 0) red[w2] = acc;
    bar_lgkm();
    if (t == 0)
        partials[blockIdx.x] = red[0] + red[1] + red[2] + red[3];
}

// ---------------- Norm: 1024 partials -> scale = cos(theta[0]/2)/sqrt(sum) ---------
__global__ void qnn_norm(const double* __restrict__ partials,
                         const float* __restrict__ theta,
                         double* __restrict__ scale) {
    __shared__ double w[4];
    const int t = threadIdx.x;
    double acc = 0.0;
    for (int i = t; i < 1024; i += 256) acc += partials[i];
#pragma unroll
    for (int off = 32; off > 0; off >>= 1) acc += __shfl_down(acc, off, 64);
    if ((t & 63) == 0) w[t >> 6] = acc;
    __syncthreads();
    if (t == 0) {
        double tot = w[0] + w[1] + w[2] + w[3];
        *scale = (double)cosf(0.5f * theta[0]) / sqrt(tot);
    }
}

// ---------------- qnn_high: pairs j7..j11 (el bits 14..23) + scale, in place -------
// Tile: slot s (13 bits) = H<<3 | pq; H = el bits 14..23, pq = el bits 2..4.
// Global quad = b24<<22 | H<<12 | mid<<3 | pq (mid = el bits 5..13, grid 512;
// both b24 tiles per block). 128 B granules at 64 KB stride.
// Load layout s = k<<9 | t (512 thr, k=0..15): j7 = s bits 4,3 (lane shfl);
// j10 = s bits 10,9 = k bits 1,0; j11 = s bits 12,11 = k bits 3,2.
// LDS exchange to s' = w3<<10 | (lane>>5)<<9 | m<<5 | (lane&31):
// j8 = s bits 6,5 = m bits 1,0; j9 = s bits 8,7 = m bits 3,2. NT store at s'.
// REGULAR loads (r12 A/B: NT loads here = 35->80us regression).
__global__ __launch_bounds__(512, 2) void qnn_high(float* __restrict__ buf,
                                                   const float* __restrict__ theta,
                                                   const double* __restrict__ scale) {
    __shared__ __align__(16) float4 lds[8192];   // 128 KB
    const int t = threadIdx.x, lane = t & 63, w3 = t >> 6;
    const int mid = blockIdx.x;
    const long gqA = (long)mid << 3;                 // b24 = 0
    const long gqB = (1L << 22) | ((long)mid << 3);  // b24 = 1

    float c7,s7,c8,s8,c9,s9,c10,s10,c11,s11;
    { float th;
      th=0.5f*theta[4]; c7 =cosf(th); s7 =sinf(th);
      th=0.5f*theta[3]; c8 =cosf(th); s8 =sinf(th);
      th=0.5f*theta[2]; c9 =cosf(th); s9 =sinf(th);
      th=0.5f*theta[1]; c10=cosf(th); s10=sinf(th);
      th=0.5f*theta[0]; c11=cosf(th); s11=sinf(th); }
    const float sc = (float)(*scale);

    const int rbase = (w3 << 10) | ((lane >> 5) << 9) | (lane & 31);  // read base

    float4 f[16], g[16];
    // ---- issue ALL 32 loads (regular) ----
#pragma unroll
    for (int k = 0; k < 16; ++k) {
        const int s_ = (k << 9) | t;
        f[k] = *(const float4*)(buf + ((gqA | ((long)(s_ >> 3) << 12) | (s_ & 7)) << 2));
    }
#pragma unroll
    for (int k = 0; k < 16; ++k) {
        const int s_ = (k << 9) | t;
        g[k] = *(const float4*)(buf + ((gqB | ((long)(s_ >> 3) << 12) | (s_ & 7)) << 2));
    }

    // ---- tile A: j7 (shfl), j10/j11 (regs) ----
    rotshfl<16>(f, 3, c7, s7, lane);
#pragma unroll
    for (int hi = 0; hi < 16; hi += 4) rot4(f[hi+1], f[hi+2], c10, s10);
#pragma unroll
    for (int lo = 0; lo < 4; ++lo)     rot4(f[4+lo], f[8+lo], c11, s11);
#pragma unroll
    for (int k = 0; k < 16; ++k) lds[(k << 9) | t] = f[k];
    bar_lgkm();
    // ---- read A; j8/j9 (regs); scale; NT store ----
#pragma unroll
    for (int m = 0; m < 16; ++m) f[m] = lds[rbase | (m << 5)];
#pragma unroll
    for (int hi = 0; hi < 16; hi += 4) rot4(f[hi+1], f[hi+2], c8, s8);
#pragma unroll
    for (int lo = 0; lo < 4; ++lo)     rot4(f[4+lo], f[8+lo], c9, s9);
#pragma unroll
    for (int m = 0; m < 16; ++m) {
        const int s_ = rbase | (m << 5);
        float4 v = f[m];
        v.x *= sc; v.y *= sc; v.z *= sc; v.w *= sc;
        nt_store4(buf + ((gqA | ((long)(s_ >> 3) << 12) | (s_ & 7)) << 2), v);
    }

    // ---- tile B ----
    rotshfl<16>(g, 3, c7, s7, lane);
#pragma unroll
    for (int hi = 0; hi < 16; hi += 4) rot4(g[hi+1], g[hi+2], c10, s10);
#pragma unroll
    for (int lo = 0; lo < 4; ++lo)     rot4(g[4+lo], g[8+lo], c11, s11);
    bar_lgkm();   // all waves done reading A's LDS image
#pragma unroll
    for (int k = 0; k < 16; ++k) lds[(k << 9) | t] = g[k];
    bar_lgkm();
#pragma unroll
    for (int m = 0; m < 16; ++m) g[m] = lds[rbase | (m << 5)];
#pragma unroll
    for (int hi = 0; hi < 16; hi += 4) rot4(g[hi+1], g[hi+2], c8, s8);
#pragma unroll
    for (int lo = 0; lo < 4; ++lo)     rot4(g[4+lo], g[8+lo], c9, s9);
#pragma unroll
    for (int m = 0; m < 16; ++m) {
        const int s_ = rbase | (m << 5);
        float4 v = g[m];
        v.x *= sc; v.y *= sc; v.z *= sc; v.w *= sc;
        nt_store4(buf + ((gqB | ((long)(s_ >> 3) << 12) | (s_ & 7)) << 2), v);
    }
}

extern "C" void kernel_launch(void* const* d_in, const int* in_sizes, int n_in,
                              void* d_out, int out_size, void* d_ws, size_t ws_size,
                              hipStream_t stream) {
    const float* in = (const float*)d_in[0];      // feature, 2^25 f32
    const float* theta = (const float*)d_in[1];   // 13 f32
    float* out = (float*)d_out;                   // 2^25 f32
    double* part = (double*)d_ws;                 // 1024 partials + 1 scale
    double* scale = part + 1024;

    qnn_p1<<<1024, 256, 0, stream>>>(in, theta, out, part);
    qnn_norm<<<1, 256, 0, stream>>>(part, theta, scale);
    qnn_high<<<512, 512, 0, stream>>>(out, theta, scale);
}

// Round 14
// 93.618 us; speedup vs baseline: 1.3183x; 1.0419x over previous
//
#include <hip/hip_runtime.h>
#include <math.h>

// NaiveDFTQNN: 25-wire state vector, DIM = 2^25.
// out = (cos(theta[0]/2)/||f||) * (tensor product of 12 Givens rotations) * f
// Pair j (j=0..11) acts on little-endian element bits (2j+1, 2j), angle theta[11-j]/2:
//   v=01: n01 = c*a01 - s*a10 ; v=10: n10 = s*a01 + c*a10 ; v=00,11 untouched.
// Bit 24 (wire 0) is a spectator (RX folds into the scalar).
//
// Cache-steering ledger (A/B-mapped r6..r13): `in` NT-load; intermediate regular
// store + regular load; final NT-store. NT anywhere on the intermediate loses.
// p1 (41 us, ~6.2 TB/s = at copy ceiling): 256 thr x 16 quads x 2 tiles, all 32
// loads upfront, 64 KB LDS, lgkm-only barriers, fp32 pairwise sumsq.
// r14 experiment (single variable): high's granule 128 B -> 256 B.
//   Tile = H(9 bits: el 14..22) x payload(16 quads: el 2..5) = 8192 quads, 128 KB.
//   Displaced pair j11 (el 23,22) done cross-register-tile: block holds b23=0 (f)
//   and b23=1 (g); el22 = k bit 3 -> rot4(f[8+i], g[i]). b24 moved to grid.

typedef float f32x4 __attribute__((ext_vector_type(4)));

static __device__ __forceinline__ float4 nt_load4(const float* p) {
    f32x4 v = __builtin_nontemporal_load((const f32x4*)p);
    return *(float4*)&v;
}
static __device__ __forceinline__ void nt_store4(float* p, float4 v) {
    __builtin_nontemporal_store(*(f32x4*)&v, (f32x4*)p);
}

// Barrier that drains ONLY lgkmcnt (LDS) — global loads/stores stay in flight.
static __device__ __forceinline__ void bar_lgkm() {
    asm volatile("s_waitcnt lgkmcnt(0)\n\ts_barrier" ::: "memory");
}

static __device__ __forceinline__ void rot4(float4& a, float4& b, float c, float s) {
    float4 na, nb;
    na.x = c*a.x - s*b.x;  nb.x = s*a.x + c*b.x;
    na.y = c*a.y - s*b.y;  nb.y = s*a.y + c*b.y;
    na.z = c*a.z - s*b.z;  nb.z = s*a.z + c*b.z;
    na.w = c*a.w - s*b.w;  nb.w = s*a.w + c*b.w;
    a = na; b = nb;
}

static __device__ __forceinline__ float4 shflx4(float4 v, int m) {
    float4 r;
    r.x = __shfl_xor(v.x, m, 64);
    r.y = __shfl_xor(v.y, m, 64);
    r.z = __shfl_xor(v.z, m, 64);
    r.w = __shfl_xor(v.w, m, 64);
    return r;
}

template <int NR>
static __device__ __forceinline__ void rotshfl(float4* f, int sh, float c, float s, int lane) {
    const int pv = (lane >> sh) & 3;
    const bool act = (pv == 1) || (pv == 2);
    const float cl = act ? c : 1.0f;
    const float sl = act ? ((pv == 1) ? -s : s) : 0.0f;
    const int m = 3 << sh;
#pragma unroll
    for (int k = 0; k < NR; ++k) {
        float4 p = shflx4(f[k], m);
        float4 n;
        n.x = fmaf(sl, p.x, cl * f[k].x);
        n.y = fmaf(sl, p.y, cl * f[k].y);
        n.z = fmaf(sl, p.z, cl * f[k].z);
        n.w = fmaf(sl, p.w, cl * f[k].w);
        f[k] = n;
    }
}

// fp32 pairwise-tree sum of squares over 16 float4 (64 values).
static __device__ __forceinline__ float sumsq16(const float4* f) {
    float q[16];
#pragma unroll
    for (int k = 0; k < 16; ++k)
        q[k] = fmaf(f[k].x, f[k].x,
               fmaf(f[k].y, f[k].y,
               fmaf(f[k].z, f[k].z, f[k].w * f[k].w)));
#pragma unroll
    for (int st = 1; st < 16; st <<= 1)
#pragma unroll
        for (int i = 0; i < 16; i += (st << 1))
            q[i] += q[i + st];
    return q[0];
}

// ---------------- qnn_p1: pairs j0..j6 (el bits 0..13), in -> out, + partials ------
// (unchanged r13 champion leg: ~41 us, ~6.2 TB/s effective)
__global__ __launch_bounds__(256, 2) void qnn_p1(const float* __restrict__ in,
                                                 const float* __restrict__ theta,
                                                 float* __restrict__ out,
                                                 double* __restrict__ partials) {
    __shared__ __align__(16) float4 lds[4096];   // 64 KB
    __shared__ double red[4];
    const int t = threadIdx.x, lane = t & 63, w2 = t >> 6;
    const long gA = (long)blockIdx.x << 13;      // quad base, tile A
    const long gB = gA + 4096;                   // tile B

    float c0,s0,c1,s1,c2,s2,c3,s3,c4,s4,c5,s5,c6,s6;
    { float th;
      th=0.5f*theta[11]; c0=cosf(th); s0=sinf(th);
      th=0.5f*theta[10]; c1=cosf(th); s1=sinf(th);
      th=0.5f*theta[9];  c2=cosf(th); s2=sinf(th);
      th=0.5f*theta[8];  c3=cosf(th); s3=sinf(th);
      th=0.5f*theta[7];  c4=cosf(th); s4=sinf(th);
      th=0.5f*theta[6];  c5=cosf(th); s5=sinf(th);
      th=0.5f*theta[5];  c6=cosf(th); s6=sinf(th); }

    float4 f[16], g[16];
#pragma unroll
    for (int k = 0; k < 16; ++k)
        f[k] = nt_load4(in + ((gA + ((w2 << 10) | (k << 6) | lane)) << 2));
#pragma unroll
    for (int k = 0; k < 16; ++k)
        g[k] = nt_load4(in + ((gB + ((w2 << 10) | (k << 6) | lane)) << 2));

    const float sA = sumsq16(f);

#pragma unroll
    for (int k = 0; k < 16; ++k) {
        float ny = c0*f[k].y - s0*f[k].z;
        float nz = s0*f[k].y + c0*f[k].z;
        f[k].y = ny; f[k].z = nz;
    }
    rotshfl<16>(f, 0, c1, s1, lane);
    rotshfl<16>(f, 2, c2, s2, lane);
    rotshfl<16>(f, 4, c3, s3, lane);
#pragma unroll
    for (int hi = 0; hi < 16; hi += 4) rot4(f[hi+1], f[hi+2], c4, s4);
#pragma unroll
    for (int lo = 0; lo < 4; ++lo)     rot4(f[4+lo], f[8+lo], c5, s5);

#pragma unroll
    for (int k = 0; k < 16; ++k) lds[(w2 << 10) | (k << 6) | lane] = f[k];
    bar_lgkm();
#pragma unroll
    for (int m = 0; m < 16; ++m) f[m] = lds[(m << 8) | (w2 << 6) | lane];
#pragma unroll
    for (int lo = 0; lo < 4; ++lo) rot4(f[4+lo], f[8+lo], c6, s6);
#pragma unroll
    for (int m = 0; m < 16; ++m)
        *(float4*)(out + ((gA + ((m << 8) | (w2 << 6) | lane)) << 2)) = f[m];

    const float sB = sumsq16(g);
#pragma unroll
    for (int k = 0; k < 16; ++k) {
        float ny = c0*g[k].y - s0*g[k].z;
        float nz = s0*g[k].y + c0*g[k].z;
        g[k].y = ny; g[k].z = nz;
    }
    rotshfl<16>(g, 0, c1, s1, lane);
    rotshfl<16>(g, 2, c2, s2, lane);
    rotshfl<16>(g, 4, c3, s3, lane);
#pragma unroll
    for (int hi = 0; hi < 16; hi += 4) rot4(g[hi+1], g[hi+2], c4, s4);
#pragma unroll
    for (int lo = 0; lo < 4; ++lo)     rot4(g[4+lo], g[8+lo], c5, s5);

    bar_lgkm();
#pragma unroll
    for (int k = 0; k < 16; ++k) lds[(w2 << 10) | (k << 6) | lane] = g[k];
    bar_lgkm();
#pragma unroll
    for (int m = 0; m < 16; ++m) g[m] = lds[(m << 8) | (w2 << 6) | lane];
#pragma unroll
    for (int lo = 0; lo < 4; ++lo) rot4(g[4+lo], g[8+lo], c6, s6);
#pragma unroll
    for (int m = 0; m < 16; ++m)
        *(float4*)(out + ((gB + ((m << 8) | (w2 << 6) | lane)) << 2)) = g[m];

    double acc = (double)sA + (double)sB;
#pragma unroll
    for (int off = 32; off > 0; off >>= 1) acc += __shfl_down(acc, off, 64);
    if (lane == 0) red[w2] = acc;
    bar_lgkm();
    if (t == 0)
        partials[blockIdx.x] = red[0] + red[1] + red[2] + red[3];
}

// ---------------- Norm: 1024 partials -> scale = cos(theta[0]/2)/sqrt(sum) ---------
__global__ void qnn_norm(const double* __restrict__ partials,
                         const float* __restrict__ theta,
                         double* __restrict__ scale) {
    __shared__ double w[4];
    const int t = threadIdx.x;
    double acc = 0.0;
    for (int i = t; i < 1024; i += 256) acc += partials[i];
#pragma unroll
    for (int off = 32; off > 0; off >>= 1) acc += __shfl_down(acc, off, 64);
    if ((t & 63) == 0) w[t >> 6] = acc;
    __syncthreads();
    if (t == 0) {
        double tot = w[0] + w[1] + w[2] + w[3];
        *scale = (double)cosf(0.5f * theta[0]) / sqrt(tot);
    }
}

// ---------------- qnn_high: pairs j7..j11 (el bits 14..23) + scale, in place -------
// r14: 256 B granules. Tile slot s (13 bits) = H<<4 | pq; H = el bits 14..22
// (9 bits), pq = el bits 2..5 (4 quads..16 quads contiguous = 256 B granule).
// Global quad = b24<<22 | b23<<21 | (s>>4)<<12 | mid<<4 | (s&15);
// grid bid = b24<<8 | mid (512 blocks); block holds BOTH b23 tiles in regs
// (f = b23:0, g = b23:1), 16 quads each (512 thr).
// Load layout s = k<<9 | t: j7 = s(5,4) = lane shfl sh=4; j10 = s(11,10) =
// k(2,1) -> (f2,f4),(f3,f5),(f10,f12),(f11,f13); j11 = (b23, s12=k3) ->
// rot4(f[8+i], g[i]).
// Read layout s' = (t>>6)<<10 | m<<6 | (t&63): j8 = s(7,6) = m(1,0) ->
// rot4(r[4q+1],r[4q+2]); j9 = s(9,8) = m(3,2) -> rot4(r[4+lo],r[8+lo]).
// Regular loads (IC-resident intermediate), NT final stores. 3 lgkm barriers.
__global__ __launch_bounds__(512, 2) void qnn_high(float* __restrict__ buf,
                                                   const float* __restrict__ theta,
                                                   const double* __restrict__ scale) {
    __shared__ __align__(16) float4 lds[8192];   // 128 KB
    const int t = threadIdx.x, lane = t & 63;
    const int bid = blockIdx.x;
    const int b24 = bid >> 8, mid = bid & 255;
    const long baseA = ((long)b24 << 22) | ((long)mid << 4);   // b23 = 0
    const long baseB = baseA | (1L << 21);                     // b23 = 1

    float c7,s7,c8,s8,c9,s9,c10,s10,c11,s11;
    { float th;
      th=0.5f*theta[4]; c7 =cosf(th); s7 =sinf(th);
      th=0.5f*theta[3]; c8 =cosf(th); s8 =sinf(th);
      th=0.5f*theta[2]; c9 =cosf(th); s9 =sinf(th);
      th=0.5f*theta[1]; c10=cosf(th); s10=sinf(th);
      th=0.5f*theta[0]; c11=cosf(th); s11=sinf(th); }
    const float sc = (float)(*scale);

    float4 f[16], g[16];
    // ---- issue ALL 32 loads (regular; 256 B granules at 64 KB stride) ----
#pragma unroll
    for (int k = 0; k < 16; ++k) {
        const int s_ = (k << 9) | t;
        f[k] = *(const float4*)(buf + ((baseA | ((long)(s_ >> 4) << 12) | (s_ & 15)) << 2));
    }
#pragma unroll
    for (int k = 0; k < 16; ++k) {
        const int s_ = (k << 9) | t;
        g[k] = *(const float4*)(buf + ((baseB | ((long)(s_ >> 4) << 12) | (s_ & 15)) << 2));
    }

    // ---- register rotations: j7 (shfl), j10 (k regs), j11 (cross f/g) ----
    rotshfl<16>(f, 4, c7, s7, lane);
    rotshfl<16>(g, 4, c7, s7, lane);
#pragma unroll
    for (int h8 = 0; h8 < 16; h8 += 8) {           // j10: k bits 2,1
        rot4(f[h8+2], f[h8+4], c10, s10);
        rot4(f[h8+3], f[h8+5], c10, s10);
        rot4(g[h8+2], g[h8+4], c10, s10);
        rot4(g[h8+3], g[h8+5], c10, s10);
    }
#pragma unroll
    for (int i = 0; i < 8; ++i)                    // j11: (b23, k bit 3)
        rot4(f[8+i], g[i], c11, s11);

    // ---- tile A (b23=0): LDS trip for j8/j9, scale, NT store ----
#pragma unroll
    for (int k = 0; k < 16; ++k) lds[(k << 9) | t] = f[k];
    bar_lgkm();
    {
        const int rb = ((t >> 6) << 10) | (t & 63);
#pragma unroll
        for (int m = 0; m < 16; ++m) f[m] = lds[rb | (m << 6)];
#pragma unroll
        for (int q = 0; q < 16; q += 4) rot4(f[q+1], f[q+2], c8, s8);   // j8
#pragma unroll
        for (int lo = 0; lo < 4; ++lo)  rot4(f[4+lo], f[8+lo], c9, s9); // j9
#pragma unroll
        for (int m = 0; m < 16; ++m) {
            const int s_ = rb | (m << 6);
            float4 v = f[m];
            v.x *= sc; v.y *= sc; v.z *= sc; v.w *= sc;
            nt_store4(buf + ((baseA | ((long)(s_ >> 4) << 12) | (s_ & 15)) << 2), v);
        }
    }
    bar_lgkm();   // all waves done reading A's LDS image

    // ---- tile B (b23=1) ----
#pragma unroll
    for (int k = 0; k < 16; ++k) lds[(k << 9) | t] = g[k];
    bar_lgkm();
    {
        const int rb = ((t >> 6) << 10) | (t & 63);
#pragma unroll
        for (int m = 0; m < 16; ++m) g[m] = lds[rb | (m << 6)];
#pragma unroll
        for (int q = 0; q < 16; q += 4) rot4(g[q+1], g[q+2], c8, s8);   // j8
#pragma unroll
        for (int lo = 0; lo < 4; ++lo)  rot4(g[4+lo], g[8+lo], c9, s9); // j9
#pragma unroll
        for (int m = 0; m < 16; ++m) {
            const int s_ = rb | (m << 6);
            float4 v = g[m];
            v.x *= sc; v.y *= sc; v.z *= sc; v.w *= sc;
            nt_store4(buf + ((baseB | ((long)(s_ >> 4) << 12) | (s_ & 15)) << 2), v);
        }
    }
}

extern "C" void kernel_launch(void* const* d_in, const int* in_sizes, int n_in,
                              void* d_out, int out_size, void* d_ws, size_t ws_size,
                              hipStream_t stream) {
    const float* in = (const float*)d_in[0];      // feature, 2^25 f32
    const float* theta = (const float*)d_in[1];   // 13 f32
    float* out = (float*)d_out;                   // 2^25 f32
    double* part = (double*)d_ws;                 // 1024 partials + 1 scale
    double* scale = part + 1024;

    qnn_p1<<<1024, 256, 0, stream>>>(in, theta, out, part);
    qnn_norm<<<1, 256, 0, stream>>>(part, theta, scale);
    qnn_high<<<512, 512, 0, stream>>>(out, theta, scale);
}